// Round 9
// baseline (145.925 us; speedup 1.0000x reference)
//
#include <hip/hip_runtime.h>
#include <hip/hip_cooperative_groups.h>
#include <math.h>

namespace coopg = cooperative_groups;

#define BB 2
#define PP 4096
#define CC 64
#define SZ 128
#define KK 8

// radius = 1.5/128*2 = 0.0234375 (exact); r^2 = 9*2^-14 (exact)
#define R2f 0.00054931640625f
#define SLOTS 16          // per-pixel slot cap (Poisson mean 1.77; P(>=16) ~ 1e-9)
#define CHG 16            // channels per composite thread (one cache line/slot)

typedef unsigned long long u64;
#define EMPTYK (~0ull)

// ---- single cooperative kernel: transpose+clear | bin | select+composite+bg
// 512 blocks x 256 threads (2 blocks/CU -> co-resident for grid.sync()).
__global__ __launch_bounds__(256) void mega_kernel(const float* __restrict__ pts,
                                                   const float* __restrict__ src,
                                                   float* __restrict__ srcT,
                                                   int* __restrict__ cnt,
                                                   u64* __restrict__ keys,
                                                   float* __restrict__ out,
                                                   float* __restrict__ bgout) {
    coopg::grid_group grid = coopg::this_grid();
    const int tidb = threadIdx.x;
    const int blk  = blockIdx.x;               // 0..511
    const int gtid = blk * 256 + tidb;         // 0..131071

    __shared__ float lt[64][65];

    // ================= phase 0: src transpose (blk<128) + cnt clear =========
    if (blk < 128) {
        // [C][P] -> [P][C] via LDS 64x65 (R8-proven indexing)
        const int b2  = blk >> 6;
        const int p0  = (blk & 63) << 6;
        const int rr  = tidb >> 6;             // 0..3
        const int ccl = tidb & 63;
#pragma unroll
        for (int k = 0; k < 16; ++k) {
            const int c = k * 4 + rr;
            lt[c][ccl] = src[(size_t)((b2 * CC + c) << 12 | (p0 + ccl))];
        }
        __syncthreads();
#pragma unroll
        for (int k = 0; k < 16; ++k) {
            const int pl = k * 4 + rr;
            srcT[(size_t)(((b2 << 12) | (p0 + pl)) << 6 | ccl)] = lt[ccl][pl];
        }
    } else if (blk < 256) {
        cnt[gtid - 32768] = 0;                 // npix = 32768 ints
    }

    grid.sync();

    // ================= phase 1: point-parallel exact binning =================
    // 4 threads/point (thread r = candidate row), bit-exact reference test;
    // unique totally-ordered (z_bits,idx) keys -> any atomic order is fine.
    if (gtid < BB * PP * 4) {
        const int r  = gtid & 3;
        const int gp = gtid >> 2;              // 0 .. BB*PP-1
        const int b  = gp >> 12;
        const int p  = gp & (PP - 1);
        const float px = pts[(size_t)gp * 3 + 0];
        const float py = pts[(size_t)gp * 3 + 1];
        const float pz = pts[(size_t)gp * 3 + 2];
        if (pz > 0.0f) {
            // gx(w) = 1-(2w+1)/128 equals -px at w = (1+px)*64 - 0.5
            const float u = (1.0f + px) * 64.0f - 0.5f;
            const float v = (1.0f + py) * 64.0f - 0.5f;
            const int wlo = max(0,   (int)ceilf (u - 1.53f));
            const int whi = min(127, (int)floorf(u + 1.53f));
            const int hlo = max(0,   (int)ceilf (v - 1.53f));
            const int hhi = min(127, (int)floorf(v + 1.53f));
            const int h = hlo + r;
            if (h <= hhi && wlo <= whi) {
                const float gy  = 1.0f - (2 * h + 1) * (1.0f / 128.0f);
                const float dy  = __fadd_rn(gy, py);       // ref: gy - (-py)
                const float dy2 = __fmul_rn(dy, dy);
                const u64 zkey = ((u64)__float_as_uint(pz) << 32) | (unsigned)p;
                for (int w = wlo; w <= whi; ++w) {
                    const float gx = 1.0f - (2 * w + 1) * (1.0f / 128.0f);
                    const float dx = __fadd_rn(gx, px);
                    const float d2 = __fadd_rn(__fmul_rn(dx, dx), dy2);
                    if (d2 < R2f) {
                        const int pix = (b << 14) | (h << 7) | w;
                        const int pos = atomicAdd(cnt + pix, 1);
                        if (pos < SLOTS) keys[pix * SLOTS + pos] = zkey;
                    }
                }
            }
        }
    }

    grid.sync();

    // ================= phase 2: select + weights + composite + bg ===========
    {
        const int pix  = gtid & 16383;
        const int cgp  = (gtid >> 14) & 3;     // 4 groups of 16 channels
        const int b    = gtid >> 16;
        const int gpix = (b << 14) | pix;

        int n = cnt[gpix];
        n = (n > SLOTS) ? SLOTS : n;

        // K smallest (z, idx) via 8-deep sorted insertion on packed u64 keys.
        u64 kk[KK];
#pragma unroll
        for (int s = 0; s < KK; ++s) kk[s] = EMPTYK;
        for (int j = 0; j < n; ++j) {
            u64 kn = keys[gpix * SLOTS + j];
#pragma unroll
            for (int s = 0; s < KK; ++s) {
                if (kn < kk[s]) { u64 tk = kk[s]; kk[s] = kn; kn = tk; }
            }
        }

        const int w = pix & 127;
        const int h = pix >> 7;
        const float gx = 1.0f - (2 * w + 1) * (1.0f / 128.0f);
        const float gy = 1.0f - (2 * h + 1) * (1.0f / 128.0f);

        float acc[CHG];
#pragma unroll
        for (int c = 0; c < CHG; ++c) acc[c] = 0.0f;

        float T = 1.0f;
#pragma unroll
        for (int s = 0; s < KK; ++s) {
            if (kk[s] == EMPTYK) break;        // filled slots form a prefix
            const int id = (int)(kk[s] & 0xffffffffu);
            // recompute d2 bit-exactly (pts is L1/L2-resident, 96KB)
            const float* q = pts + (size_t)((b << 12) + id) * 3;
            const float dx = __fadd_rn(gx, q[0]);
            const float dy = __fadd_rn(gy, q[1]);
            const float d2 = __fadd_rn(__fmul_rn(dx, dx), __fmul_rn(dy, dy));
            float dn = d2 / R2f;
            dn = fminf(fmaxf(dn, 0.001f), 1.0f);
            const float a  = 1.0f - sqrtf(dn);
            const float wt = a * T;
            T = T * (1.0f - a);
            const float* fp = srcT + ((size_t)((b << 12) + id) << 6) + cgp * CHG;
#pragma unroll
            for (int v4 = 0; v4 < CHG / 4; ++v4) {
                const float4 f = *(const float4*)(fp + v4 * 4);
                acc[v4 * 4 + 0] = fmaf(wt, f.x, acc[v4 * 4 + 0]);
                acc[v4 * 4 + 1] = fmaf(wt, f.y, acc[v4 * 4 + 1]);
                acc[v4 * 4 + 2] = fmaf(wt, f.z, acc[v4 * 4 + 2]);
                acc[v4 * 4 + 3] = fmaf(wt, f.w, acc[v4 * 4 + 3]);
            }
        }
#pragma unroll
        for (int c = 0; c < CHG; ++c)
            out[((size_t)(b * CC + cgp * CHG + c) << 14) | pix] = acc[c];

        // background: dilate(cnt==0) over 3x3 — cgp==0 threads own their pixel
        if (cgp == 0) {
            int bgv = 0;
#pragma unroll
            for (int dh = -1; dh <= 1; ++dh)
#pragma unroll
                for (int dw = -1; dw <= 1; ++dw) {
                    const int hh = h + dh, ww = w + dw;
                    if (hh >= 0 && hh < 128 && ww >= 0 && ww < 128)
                        if (cnt[(b << 14) | (hh << 7) | ww] == 0) bgv = 1;
                }
            bgout[gpix] = bgv ? 1.0f : 0.0f;
        }
    }
}

extern "C" void kernel_launch(void* const* d_in, const int* in_sizes, int n_in,
                              void* d_out, int out_size, void* d_ws, size_t ws_size,
                              hipStream_t stream) {
    const float* pts = (const float*)d_in[0];   // [B,P,3]
    const float* src = (const float*)d_in[1];   // [B,C,P]
    float* out = (float*)d_out;                 // [B,C,H,W] then bg [B,H,W]
    float* bgout = out + BB * CC * SZ * SZ;

    const int npix = BB * SZ * SZ;              // 32768
    char* ws = (char*)d_ws;
    float* srcT = (float*)ws;                                  // 2 MB
    int*   cnt  = (int*)(ws + (size_t)BB * PP * CC * 4);       // 128 KB
    u64*   keys = (u64*)(ws + (size_t)BB * PP * CC * 4 + (size_t)npix * 4); // 4 MB

    void* args[] = { (void*)&pts, (void*)&src, (void*)&srcT, (void*)&cnt,
                     (void*)&keys, (void*)&out, (void*)&bgout };
    hipLaunchCooperativeKernel((void*)mega_kernel, dim3(512), dim3(256),
                               args, 0, stream);
}

// Round 10
// 30.599 us; speedup vs baseline: 4.7690x; 4.7690x over previous
//
#include <hip/hip_runtime.h>
#include <math.h>

#define BB 2
#define PP 4096
#define CC 64
#define SZ 128
#define KK 8

// radius = 1.5/128*2 = 0.0234375 (exact); r^2 = 9*2^-14 (exact)
#define R2f 0.00054931640625f

typedef unsigned long long u64;
#define EMPTYK (~0ull)

// ---- Node 1: clear per-pixel key slots + src transpose [C][P]->[P][C] ------
// 512 blocks: blk<128 transpose (R8-proven), blk>=128 clear 262144 u64 keys.
__global__ __launch_bounds__(256) void prep_kernel(const float* __restrict__ src,
                                                   float* __restrict__ srcT,
                                                   u64* __restrict__ keys) {
    const int tidb = threadIdx.x;
    const int blk  = blockIdx.x;
    if (blk < 128) {
        __shared__ float lt[64][65];
        const int b2  = blk >> 6;
        const int p0  = (blk & 63) << 6;
        const int rr  = tidb >> 6;             // 0..3
        const int ccl = tidb & 63;
#pragma unroll
        for (int k = 0; k < 16; ++k) {
            const int c = k * 4 + rr;
            lt[c][ccl] = src[(size_t)((b2 * CC + c) << 12 | (p0 + ccl))];
        }
        __syncthreads();
#pragma unroll
        for (int k = 0; k < 16; ++k) {
            const int pl = k * 4 + rr;
            srcT[(size_t)(((b2 << 12) | (p0 + pl)) << 6 | ccl)] = lt[ccl][pl];
        }
    } else {
        const int base = (blk - 128) * 256 + tidb;      // 0..98303
        for (int i = base; i < BB * SZ * SZ * KK; i += 384 * 256)
            keys[i] = EMPTYK;
    }
}

// ---- Node 2: point-parallel exact binning, atomicMin-cascade K-buffer ------
// 4 threads/point (thread r = candidate row), bit-exact reference test.
// Sorted-insertion via atomicMin chain: final slots = 8 smallest (z,idx) keys
// in ascending order, deterministic under any atomic interleaving.
__global__ __launch_bounds__(256) void bin_kernel(const float* __restrict__ pts,
                                                  u64* __restrict__ keys) {
    const int t  = blockIdx.x * 256 + threadIdx.x;   // 0 .. BB*PP*4-1
    const int r  = t & 3;
    const int gp = t >> 2;                           // 0 .. BB*PP-1
    const int b  = gp >> 12;
    const int p  = gp & (PP - 1);
    const float px = pts[(size_t)gp * 3 + 0];
    const float py = pts[(size_t)gp * 3 + 1];
    const float pz = pts[(size_t)gp * 3 + 2];
    if (!(pz > 0.0f)) return;
    // gx(w) = 1-(2w+1)/128 equals -px at w = (1+px)*64 - 0.5
    const float u = (1.0f + px) * 64.0f - 0.5f;
    const float v = (1.0f + py) * 64.0f - 0.5f;
    const int wlo = max(0,   (int)ceilf (u - 1.53f));
    const int whi = min(127, (int)floorf(u + 1.53f));
    const int hlo = max(0,   (int)ceilf (v - 1.53f));
    const int hhi = min(127, (int)floorf(v + 1.53f));
    const int h = hlo + r;
    if (h > hhi || wlo > whi) return;

    const float gy  = 1.0f - (2 * h + 1) * (1.0f / 128.0f);
    const float dy  = __fadd_rn(gy, py);             // ref: gy - (-py)
    const float dy2 = __fmul_rn(dy, dy);
    const u64 zkey = ((u64)__float_as_uint(pz) << 32) | (unsigned)p;

    for (int w = wlo; w <= whi; ++w) {
        const float gx = 1.0f - (2 * w + 1) * (1.0f / 128.0f);
        const float dx = __fadd_rn(gx, px);
        const float d2 = __fadd_rn(__fmul_rn(dx, dx), dy2);  // bit-exact ref
        if (d2 < R2f) {
            const int pix = (b << 14) | (h << 7) | w;
            u64 kn = zkey;
#pragma unroll
            for (int s = 0; s < KK; ++s) {
                const u64 old = atomicMin(&keys[(size_t)pix * KK + s], kn);
                kn = (old > kn) ? old : kn;          // carry larger forward
                if (kn == EMPTYK) break;
            }
        }
    }
}

// ---- Node 3: select (pre-sorted keys) + weights + composite + bg -----------
// 2048 blocks x 256. Thread = (channel-quad cq 0..15, pixel). 32 waves/CU.
__global__ __launch_bounds__(256) void selcomp_kernel(const float* __restrict__ pts,
                                                      const float* __restrict__ srcT,
                                                      const u64* __restrict__ keys,
                                                      float* __restrict__ out,
                                                      float* __restrict__ bgout) {
    const int blk = blockIdx.x;
    const int ll  = threadIdx.x & 63;
    const int cqi = threadIdx.x >> 6;          // 0..3
    const int cqg = blk & 3;                   // 0..3
    const int pg  = (blk >> 2) & 255;          // 64-pixel group
    const int b   = blk >> 10;
    const int cq  = cqg * 4 + cqi;             // channel quad: c = cq*4..cq*4+3
    const int pix = pg * 64 + ll;
    const int gpix = (b << 14) | pix;

    // keys arrive sorted ascending; walk until sentinel
    const u64* kp = keys + (size_t)gpix * KK;
    u64 kk[KK];
    {
        const ulonglong2 k0 = *(const ulonglong2*)(kp + 0);
        const ulonglong2 k1 = *(const ulonglong2*)(kp + 2);
        const ulonglong2 k2 = *(const ulonglong2*)(kp + 4);
        const ulonglong2 k3 = *(const ulonglong2*)(kp + 6);
        kk[0] = k0.x; kk[1] = k0.y; kk[2] = k1.x; kk[3] = k1.y;
        kk[4] = k2.x; kk[5] = k2.y; kk[6] = k3.x; kk[7] = k3.y;
    }

    const int w = pix & 127;
    const int h = pix >> 7;
    const float gx = 1.0f - (2 * w + 1) * (1.0f / 128.0f);
    const float gy = 1.0f - (2 * h + 1) * (1.0f / 128.0f);

    float acc0 = 0.0f, acc1 = 0.0f, acc2 = 0.0f, acc3 = 0.0f;
    float T = 1.0f;
#pragma unroll
    for (int s = 0; s < KK; ++s) {
        if (kk[s] == EMPTYK) break;            // filled slots form a prefix
        const int id = (int)(kk[s] & 0xffffffffu);
        // recompute d2 bit-exactly (pts is L1/L2-resident, 96KB)
        const float* q = pts + (size_t)((b << 12) + id) * 3;
        const float dx = __fadd_rn(gx, q[0]);
        const float dy = __fadd_rn(gy, q[1]);
        const float d2 = __fadd_rn(__fmul_rn(dx, dx), __fmul_rn(dy, dy));
        float dn = d2 / R2f;
        dn = fminf(fmaxf(dn, 0.001f), 1.0f);
        const float a  = 1.0f - sqrtf(dn);
        const float wt = a * T;
        T = T * (1.0f - a);
        const float4 f = *(const float4*)(srcT + ((size_t)((b << 12) + id) << 6) + cq * 4);
        acc0 = fmaf(wt, f.x, acc0);
        acc1 = fmaf(wt, f.y, acc1);
        acc2 = fmaf(wt, f.z, acc2);
        acc3 = fmaf(wt, f.w, acc3);
    }
    const int c0 = cq * 4;
    out[((size_t)(b * CC + c0 + 0) << 14) | pix] = acc0;
    out[((size_t)(b * CC + c0 + 1) << 14) | pix] = acc1;
    out[((size_t)(b * CC + c0 + 2) << 14) | pix] = acc2;
    out[((size_t)(b * CC + c0 + 3) << 14) | pix] = acc3;

    // background: dilate(slot0 == sentinel) over 3x3; one thread per pixel
    if (cqg == 0 && cqi == 0) {
        int bgv = 0;
#pragma unroll
        for (int dh = -1; dh <= 1; ++dh)
#pragma unroll
            for (int dw = -1; dw <= 1; ++dw) {
                const int hh = h + dh, ww = w + dw;
                if (hh >= 0 && hh < 128 && ww >= 0 && ww < 128)
                    if (keys[(size_t)((b << 14) | (hh << 7) | ww) * KK] == EMPTYK)
                        bgv = 1;
            }
        bgout[gpix] = bgv ? 1.0f : 0.0f;
    }
}

extern "C" void kernel_launch(void* const* d_in, const int* in_sizes, int n_in,
                              void* d_out, int out_size, void* d_ws, size_t ws_size,
                              hipStream_t stream) {
    const float* pts = (const float*)d_in[0];   // [B,P,3]
    const float* src = (const float*)d_in[1];   // [B,C,P]
    float* out = (float*)d_out;                 // [B,C,H,W] then bg [B,H,W]
    float* bgout = out + BB * CC * SZ * SZ;

    char* ws = (char*)d_ws;
    float* srcT = (float*)ws;                              // 2 MB
    u64*   keys = (u64*)(ws + (size_t)BB * PP * CC * 4);   // 2 MB (8B aligned)

    prep_kernel<<<512, 256, 0, stream>>>(src, srcT, keys);
    bin_kernel<<<(BB * PP * 4) / 256, 256, 0, stream>>>(pts, keys);
    selcomp_kernel<<<2048, 256, 0, stream>>>(pts, srcT, keys, out, bgout);
}

// Round 11
// 26.315 us; speedup vs baseline: 5.5453x; 1.1628x over previous
//
#include <hip/hip_runtime.h>
#include <math.h>

#define BB 2
#define PP 4096
#define CC 64
#define SZ 128
#define KK 8

// radius = 1.5/128*2 = 0.0234375 (exact); r^2 = 9*2^-14 (exact)
#define R2f 0.00054931640625f
#define SLOTS 16          // per-pixel slot cap (Poisson mean 1.77; P(>=16) ~ 1e-9)

typedef unsigned long long u64;
#define EMPTYK (~0ull)

// ---- Node 2: bin (blocks 0-127) + src transpose (blocks 128-383) -----------
__global__ __launch_bounds__(256) void prep_kernel(const float* __restrict__ pts,
                                                   const float* __restrict__ src,
                                                   float* __restrict__ srcT,
                                                   int* __restrict__ cnt,
                                                   u64* __restrict__ keys) {
    const int tidb = threadIdx.x;
    const int blk  = blockIdx.x;

    if (blk < 128) {
        // ---- bin: 4 threads/point (thread r = candidate row), bit-exact test.
        // unique totally-ordered (z_bits,idx) keys -> atomic order irrelevant.
        const int t  = blk * 256 + tidb;       // 0 .. BB*PP*4-1
        const int r  = t & 3;
        const int gp = t >> 2;                 // 0 .. BB*PP-1
        const int b  = gp >> 12;
        const int p  = gp & (PP - 1);
        const float px = pts[(size_t)gp * 3 + 0];
        const float py = pts[(size_t)gp * 3 + 1];
        const float pz = pts[(size_t)gp * 3 + 2];
        if (!(pz > 0.0f)) return;
        // gx(w) = 1-(2w+1)/128 equals -px at w = (1+px)*64 - 0.5
        const float u = (1.0f + px) * 64.0f - 0.5f;
        const float v = (1.0f + py) * 64.0f - 0.5f;
        const int wlo = max(0,   (int)ceilf (u - 1.53f));
        const int whi = min(127, (int)floorf(u + 1.53f));
        const int hlo = max(0,   (int)ceilf (v - 1.53f));
        const int hhi = min(127, (int)floorf(v + 1.53f));
        const int h = hlo + r;
        if (h > hhi || wlo > whi) return;
        const float gy  = 1.0f - (2 * h + 1) * (1.0f / 128.0f);
        const float dy  = __fadd_rn(gy, py);   // ref: gy - (-py)
        const float dy2 = __fmul_rn(dy, dy);
        const u64 zkey = ((u64)__float_as_uint(pz) << 32) | (unsigned)p;
        for (int w = wlo; w <= whi; ++w) {
            const float gx = 1.0f - (2 * w + 1) * (1.0f / 128.0f);
            const float dx = __fadd_rn(gx, px);
            const float d2 = __fadd_rn(__fmul_rn(dx, dx), dy2);  // bit-exact
            if (d2 < R2f) {
                const int pix = (b << 14) | (h << 7) | w;
                const int pos = atomicAdd(cnt + pix, 1);
                if (pos < SLOTS) keys[(size_t)pix * SLOTS + pos] = zkey;
            }
        }
    } else {
        // ---- transpose [C][P]->[P][C], split 2x finer than R8: 256 blocks,
        // each = (batch, 64-point group, 32-channel half)
        __shared__ float lt[32][65];
        const int tb  = blk - 128;             // 0..255
        const int b2  = tb >> 7;
        const int rem = tb & 127;
        const int p0  = (rem >> 1) << 6;       // 64-point group
        const int c0  = (rem & 1) << 5;        // channel half
        const int rr  = tidb >> 6;             // 0..3 (wave id)
        const int ccl = tidb & 63;
#pragma unroll
        for (int k = 0; k < 8; ++k) {
            const int c = k * 4 + rr;          // 0..31
            lt[c][ccl] = src[(size_t)((b2 * CC + c0 + c) << 12 | (p0 + ccl))];
        }
        __syncthreads();
        const int cch = tidb & 31;
        const int pl0 = tidb >> 5;             // 0..7
#pragma unroll
        for (int k = 0; k < 8; ++k) {
            const int pl = pl0 + k * 8;
            srcT[(size_t)(((b2 << 12) | (p0 + pl)) << 6) + c0 + cch] = lt[cch][pl];
        }
    }
}

// ---- Node 3: select + weights + composite + bg; CG=8, 1024 blocks ---------
// Load-batched: keys (1 round) -> {pts, feature lines} batch (1 round) -> VALU.
__global__ __launch_bounds__(256) void selcomp_kernel(const float* __restrict__ pts,
                                                      const float* __restrict__ srcT,
                                                      const int* __restrict__ cnt,
                                                      const u64* __restrict__ keys,
                                                      float* __restrict__ out,
                                                      float* __restrict__ bgout) {
    const int t    = blockIdx.x * 256 + threadIdx.x;  // 0 .. BB*8*16384-1
    const int pix  = t & 16383;
    const int cg   = (t >> 14) & 7;                   // 8 groups of 8 channels
    const int b    = t >> 17;
    const int gpix = (b << 14) | pix;

    int n = cnt[gpix];
    n = (n > SLOTS) ? SLOTS : n;

    // ---- keys: vector-load first 4 slots; sort statically (no scratch)
    const u64* kp = keys + (size_t)gpix * SLOTS;
    const ulonglong2 k01 = *(const ulonglong2*)(kp + 0);
    const ulonglong2 k23 = *(const ulonglong2*)(kp + 2);

    u64 kk[KK];
#pragma unroll
    for (int s = 0; s < KK; ++s) kk[s] = EMPTYK;
#define INSK(KN) { u64 kn = (KN); \
    _Pragma("unroll") for (int s = 0; s < KK; ++s) \
        if (kn < kk[s]) { u64 tk = kk[s]; kk[s] = kn; kn = tk; } }
    if (0 < n) INSK(k01.x);
    if (1 < n) INSK(k01.y);
    if (2 < n) INSK(k23.x);
    if (3 < n) INSK(k23.y);
    for (int j = 4; j < n; ++j) INSK(kp[j]);          // rare (n>4)
#undef INSK

    const int nv = (n < KK) ? n : KK;

    // ---- batch gather: all pts + feature-line loads independent, exec-masked
    float qx[KK], qy[KK];
    float4 f0[KK], f1[KK];
#pragma unroll
    for (int s = 0; s < KK; ++s) {
        if (s < nv) {
            const int id = (int)(kk[s] & 0xffffffffu);
            const float* q = pts + (size_t)((b << 12) + id) * 3;
            qx[s] = q[0];
            qy[s] = q[1];
            const float* fp = srcT + ((size_t)((b << 12) + id) << 6) + cg * 8;
            f0[s] = *(const float4*)fp;
            f1[s] = *(const float4*)(fp + 4);
        }
    }

    const int w = pix & 127;
    const int h = pix >> 7;
    const float gx = 1.0f - (2 * w + 1) * (1.0f / 128.0f);
    const float gy = 1.0f - (2 * h + 1) * (1.0f / 128.0f);

    // ---- pure-VALU pass: exact d2, weights, transmittance chain, FMAs
    float acc[8];
#pragma unroll
    for (int c = 0; c < 8; ++c) acc[c] = 0.0f;
    float T = 1.0f;
#pragma unroll
    for (int s = 0; s < KK; ++s) {
        if (s < nv) {
            const float dx = __fadd_rn(gx, qx[s]);    // ref: gx - (-px)
            const float dy = __fadd_rn(gy, qy[s]);
            const float d2 = __fadd_rn(__fmul_rn(dx, dx), __fmul_rn(dy, dy));
            float dn = d2 / R2f;
            dn = fminf(fmaxf(dn, 0.001f), 1.0f);
            const float a  = 1.0f - sqrtf(dn);
            const float wt = a * T;
            T = T * (1.0f - a);
            acc[0] = fmaf(wt, f0[s].x, acc[0]);
            acc[1] = fmaf(wt, f0[s].y, acc[1]);
            acc[2] = fmaf(wt, f0[s].z, acc[2]);
            acc[3] = fmaf(wt, f0[s].w, acc[3]);
            acc[4] = fmaf(wt, f1[s].x, acc[4]);
            acc[5] = fmaf(wt, f1[s].y, acc[5]);
            acc[6] = fmaf(wt, f1[s].z, acc[6]);
            acc[7] = fmaf(wt, f1[s].w, acc[7]);
        }
    }
#pragma unroll
    for (int c = 0; c < 8; ++c)
        out[((size_t)(b * CC + cg * 8 + c) << 14) | pix] = acc[c];

    // ---- background: dilate(cnt==0) over 3x3; one thread (cg==0) per pixel
    if (cg == 0) {
        int bgv = 0;
#pragma unroll
        for (int dh = -1; dh <= 1; ++dh)
#pragma unroll
            for (int dw = -1; dw <= 1; ++dw) {
                const int hh = h + dh, ww = w + dw;
                if (hh >= 0 && hh < 128 && ww >= 0 && ww < 128)
                    if (cnt[(b << 14) | (hh << 7) | ww] == 0) bgv = 1;
            }
        bgout[gpix] = bgv ? 1.0f : 0.0f;
    }
}

extern "C" void kernel_launch(void* const* d_in, const int* in_sizes, int n_in,
                              void* d_out, int out_size, void* d_ws, size_t ws_size,
                              hipStream_t stream) {
    const float* pts = (const float*)d_in[0];   // [B,P,3]
    const float* src = (const float*)d_in[1];   // [B,C,P]
    float* out = (float*)d_out;                 // [B,C,H,W] then bg [B,H,W]
    float* bgout = out + BB * CC * SZ * SZ;

    const int npix = BB * SZ * SZ;              // 32768
    char* ws = (char*)d_ws;
    float* srcT = (float*)ws;                                  // 2 MB
    int*   cnt  = (int*)(ws + (size_t)BB * PP * CC * 4);       // 128 KB
    u64*   keys = (u64*)(ws + (size_t)BB * PP * CC * 4 + (size_t)npix * 4); // 4 MB

    hipMemsetAsync(cnt, 0, (size_t)npix * 4, stream);
    prep_kernel<<<384, 256, 0, stream>>>(pts, src, srcT, cnt, keys);
    selcomp_kernel<<<(BB * 8 * SZ * SZ) / 256, 256, 0, stream>>>(
        pts, srcT, cnt, keys, out, bgout);
}

// Round 12
// 25.249 us; speedup vs baseline: 5.7795x; 1.0422x over previous
//
#include <hip/hip_runtime.h>
#include <math.h>

#define BB 2
#define PP 4096
#define CC 64
#define SZ 128
#define KK 8

// radius = 1.5/128*2 = 0.0234375 (exact); r^2 = 9*2^-14 (exact)
#define R2f 0.00054931640625f
#define SLOTS 16          // per-pixel slot cap (Poisson mean 1.77; P(>=16) ~ 1e-9)

typedef unsigned long long u64;
#define EMPTYK (~0ull)

// ---- Node 2: bin (blocks 0-255, 8 thr/point) + transpose (blocks 256-511) --
__global__ __launch_bounds__(256) void prep_kernel(const float* __restrict__ pts,
                                                   const float* __restrict__ src,
                                                   float* __restrict__ srcT,
                                                   int* __restrict__ cnt,
                                                   u64* __restrict__ keys) {
    const int tidb = threadIdx.x;
    const int blk  = blockIdx.x;

    if (blk < 256) {
        // ---- bin: 8 threads/point = (candidate row 0..3) x (w-half 0..1).
        // bit-exact reference test; unique totally-ordered (z_bits,idx) keys
        // make any atomic slot order deterministic. <=2 serial atomics/thread.
        const int t  = blk * 256 + tidb;       // 0 .. BB*PP*8-1
        const int r  = t & 7;
        const int gp = t >> 3;                 // 0 .. BB*PP-1
        const int b  = gp >> 12;
        const int p  = gp & (PP - 1);
        const float px = pts[(size_t)gp * 3 + 0];
        const float py = pts[(size_t)gp * 3 + 1];
        const float pz = pts[(size_t)gp * 3 + 2];
        if (!(pz > 0.0f)) return;
        // gx(w) = 1-(2w+1)/128 equals -px at w = (1+px)*64 - 0.5
        const float u = (1.0f + px) * 64.0f - 0.5f;
        const float v = (1.0f + py) * 64.0f - 0.5f;
        const int wlo = max(0,   (int)ceilf (u - 1.53f));
        const int whi = min(127, (int)floorf(u + 1.53f));
        const int hlo = max(0,   (int)ceilf (v - 1.53f));
        const int hhi = min(127, (int)floorf(v + 1.53f));
        const int h = hlo + (r >> 1);
        if (h > hhi || wlo > whi) return;
        const int w0 = wlo + ((r & 1) << 1);   // this thread: w0, w0+1
        if (w0 > whi) return;
        const float gy  = 1.0f - (2 * h + 1) * (1.0f / 128.0f);
        const float dy  = __fadd_rn(gy, py);   // ref: gy - (-py)
        const float dy2 = __fmul_rn(dy, dy);
        const u64 zkey = ((u64)__float_as_uint(pz) << 32) | (unsigned)p;
        const int wend = min(whi, w0 + 1);
        for (int w = w0; w <= wend; ++w) {
            const float gx = 1.0f - (2 * w + 1) * (1.0f / 128.0f);
            const float dx = __fadd_rn(gx, px);
            const float d2 = __fadd_rn(__fmul_rn(dx, dx), dy2);  // bit-exact
            if (d2 < R2f) {
                const int pix = (b << 14) | (h << 7) | w;
                const int pos = atomicAdd(cnt + pix, 1);
                if (pos < SLOTS) keys[(size_t)pix * SLOTS + pos] = zkey;
            }
        }
    } else {
        // ---- transpose [C][P]->[P][C]: 256 blocks, each = (batch,
        // 64-point group, 32-channel half); R11-proven indexing.
        __shared__ float lt[32][65];
        const int tb  = blk - 256;             // 0..255
        const int b2  = tb >> 7;
        const int rem = tb & 127;
        const int p0  = (rem >> 1) << 6;       // 64-point group
        const int c0  = (rem & 1) << 5;        // channel half
        const int rr  = tidb >> 6;             // 0..3 (wave id)
        const int ccl = tidb & 63;
#pragma unroll
        for (int k = 0; k < 8; ++k) {
            const int c = k * 4 + rr;          // 0..31
            lt[c][ccl] = src[(size_t)((b2 * CC + c0 + c) << 12 | (p0 + ccl))];
        }
        __syncthreads();
        const int cch = tidb & 31;
        const int pl0 = tidb >> 5;             // 0..7
#pragma unroll
        for (int k = 0; k < 8; ++k) {
            const int pl = pl0 + k * 8;
            srcT[(size_t)(((b2 << 12) | (p0 + pl)) << 6) + c0 + cch] = lt[cch][pl];
        }
    }
}

// ---- Node 3: select + weights + composite + bg; CG=8, 1024 blocks ---------
// Load-batched: keys (1 round) -> {pts, feature lines} batch (1 round) -> VALU.
__global__ __launch_bounds__(256) void selcomp_kernel(const float* __restrict__ pts,
                                                      const float* __restrict__ srcT,
                                                      const int* __restrict__ cnt,
                                                      const u64* __restrict__ keys,
                                                      float* __restrict__ out,
                                                      float* __restrict__ bgout) {
    const int t    = blockIdx.x * 256 + threadIdx.x;  // 0 .. BB*8*16384-1
    const int pix  = t & 16383;
    const int cg   = (t >> 14) & 7;                   // 8 groups of 8 channels
    const int b    = t >> 17;
    const int gpix = (b << 14) | pix;

    int n = cnt[gpix];
    n = (n > SLOTS) ? SLOTS : n;

    // ---- keys: vector-load first 4 slots; sort statically (no scratch)
    const u64* kp = keys + (size_t)gpix * SLOTS;
    const ulonglong2 k01 = *(const ulonglong2*)(kp + 0);
    const ulonglong2 k23 = *(const ulonglong2*)(kp + 2);

    u64 kk[KK];
#pragma unroll
    for (int s = 0; s < KK; ++s) kk[s] = EMPTYK;
#define INSK(KN) { u64 kn = (KN); \
    _Pragma("unroll") for (int s = 0; s < KK; ++s) \
        if (kn < kk[s]) { u64 tk = kk[s]; kk[s] = kn; kn = tk; } }
    if (0 < n) INSK(k01.x);
    if (1 < n) INSK(k01.y);
    if (2 < n) INSK(k23.x);
    if (3 < n) INSK(k23.y);
    for (int j = 4; j < n; ++j) INSK(kp[j]);          // rare (n>4)
#undef INSK

    const int nv = (n < KK) ? n : KK;

    // ---- batch gather: all pts + feature-line loads independent, exec-masked
    float qx[KK], qy[KK];
    float4 f0[KK], f1[KK];
#pragma unroll
    for (int s = 0; s < KK; ++s) {
        if (s < nv) {
            const int id = (int)(kk[s] & 0xffffffffu);
            const float* q = pts + (size_t)((b << 12) + id) * 3;
            qx[s] = q[0];
            qy[s] = q[1];
            const float* fp = srcT + ((size_t)((b << 12) + id) << 6) + cg * 8;
            f0[s] = *(const float4*)fp;
            f1[s] = *(const float4*)(fp + 4);
        }
    }

    const int w = pix & 127;
    const int h = pix >> 7;
    const float gx = 1.0f - (2 * w + 1) * (1.0f / 128.0f);
    const float gy = 1.0f - (2 * h + 1) * (1.0f / 128.0f);

    // ---- pure-VALU pass: exact d2, weights, transmittance chain, FMAs
    float acc[8];
#pragma unroll
    for (int c = 0; c < 8; ++c) acc[c] = 0.0f;
    float T = 1.0f;
#pragma unroll
    for (int s = 0; s < KK; ++s) {
        if (s < nv) {
            const float dx = __fadd_rn(gx, qx[s]);    // ref: gx - (-px)
            const float dy = __fadd_rn(gy, qy[s]);
            const float d2 = __fadd_rn(__fmul_rn(dx, dx), __fmul_rn(dy, dy));
            float dn = d2 / R2f;
            dn = fminf(fmaxf(dn, 0.001f), 1.0f);
            const float a  = 1.0f - sqrtf(dn);
            const float wt = a * T;
            T = T * (1.0f - a);
            acc[0] = fmaf(wt, f0[s].x, acc[0]);
            acc[1] = fmaf(wt, f0[s].y, acc[1]);
            acc[2] = fmaf(wt, f0[s].z, acc[2]);
            acc[3] = fmaf(wt, f0[s].w, acc[3]);
            acc[4] = fmaf(wt, f1[s].x, acc[4]);
            acc[5] = fmaf(wt, f1[s].y, acc[5]);
            acc[6] = fmaf(wt, f1[s].z, acc[6]);
            acc[7] = fmaf(wt, f1[s].w, acc[7]);
        }
    }
#pragma unroll
    for (int c = 0; c < 8; ++c)
        out[((size_t)(b * CC + cg * 8 + c) << 14) | pix] = acc[c];

    // ---- background: dilate(cnt==0) over 3x3; one thread (cg==0) per pixel
    if (cg == 0) {
        int bgv = 0;
#pragma unroll
        for (int dh = -1; dh <= 1; ++dh)
#pragma unroll
            for (int dw = -1; dw <= 1; ++dw) {
                const int hh = h + dh, ww = w + dw;
                if (hh >= 0 && hh < 128 && ww >= 0 && ww < 128)
                    if (cnt[(b << 14) | (hh << 7) | ww] == 0) bgv = 1;
            }
        bgout[gpix] = bgv ? 1.0f : 0.0f;
    }
}

extern "C" void kernel_launch(void* const* d_in, const int* in_sizes, int n_in,
                              void* d_out, int out_size, void* d_ws, size_t ws_size,
                              hipStream_t stream) {
    const float* pts = (const float*)d_in[0];   // [B,P,3]
    const float* src = (const float*)d_in[1];   // [B,C,P]
    float* out = (float*)d_out;                 // [B,C,H,W] then bg [B,H,W]
    float* bgout = out + BB * CC * SZ * SZ;

    const int npix = BB * SZ * SZ;              // 32768
    char* ws = (char*)d_ws;
    float* srcT = (float*)ws;                                  // 2 MB
    int*   cnt  = (int*)(ws + (size_t)BB * PP * CC * 4);       // 128 KB
    u64*   keys = (u64*)(ws + (size_t)BB * PP * CC * 4 + (size_t)npix * 4); // 4 MB

    hipMemsetAsync(cnt, 0, (size_t)npix * 4, stream);
    prep_kernel<<<512, 256, 0, stream>>>(pts, src, srcT, cnt, keys);
    selcomp_kernel<<<(BB * 8 * SZ * SZ) / 256, 256, 0, stream>>>(
        pts, srcT, cnt, keys, out, bgout);
}

// Round 13
// 24.521 us; speedup vs baseline: 5.9509x; 1.0297x over previous
//
#include <hip/hip_runtime.h>
#include <math.h>

#define BB 2
#define PP 4096
#define CC 64
#define SZ 128
#define KK 8

// radius = 1.5/128*2 = 0.0234375 (exact); r^2 = 9*2^-14 (exact)
#define R2f 0.00054931640625f
#define SLOTS 16          // per-pixel slot cap (Poisson mean 1.77; P(>=16) ~ 1e-9)

typedef unsigned long long u64;
#define EMPTYK (~0ull)

// ---- Node 2: bin (blocks 0-511, 16 thr/point) + transpose (blocks 512-767) -
__global__ __launch_bounds__(256) void prep_kernel(const float* __restrict__ pts,
                                                   const float* __restrict__ src,
                                                   float* __restrict__ srcT,
                                                   int* __restrict__ cnt,
                                                   u64* __restrict__ keys) {
    const int tidb = threadIdx.x;
    const int blk  = blockIdx.x;

    if (blk < 512) {
        // ---- bin: 16 threads/point = (row 0..3) x (w-candidate 0..3).
        // Each thread: <=1 bit-exact test, <=1 atomic (chain depth 1).
        // unique totally-ordered (z_bits,idx) keys -> atomic order irrelevant.
        const int t  = blk * 256 + tidb;       // 0 .. BB*PP*16-1
        const int r  = t & 15;
        const int gp = t >> 4;                 // 0 .. BB*PP-1
        const int b  = gp >> 12;
        const int p  = gp & (PP - 1);
        const float px = pts[(size_t)gp * 3 + 0];
        const float py = pts[(size_t)gp * 3 + 1];
        const float pz = pts[(size_t)gp * 3 + 2];
        if (!(pz > 0.0f)) return;
        // gx(w) = 1-(2w+1)/128 equals -px at w = (1+px)*64 - 0.5
        const float u = (1.0f + px) * 64.0f - 0.5f;
        const float v = (1.0f + py) * 64.0f - 0.5f;
        const int wlo = max(0,   (int)ceilf (u - 1.53f));
        const int whi = min(127, (int)floorf(u + 1.53f));
        const int hlo = max(0,   (int)ceilf (v - 1.53f));
        const int hhi = min(127, (int)floorf(v + 1.53f));
        const int h = hlo + (r >> 2);
        const int w = wlo + (r & 3);
        if (h > hhi || w > whi) return;
        const float gy  = 1.0f - (2 * h + 1) * (1.0f / 128.0f);
        const float dy  = __fadd_rn(gy, py);   // ref: gy - (-py)
        const float dy2 = __fmul_rn(dy, dy);
        const float gx = 1.0f - (2 * w + 1) * (1.0f / 128.0f);
        const float dx = __fadd_rn(gx, px);
        const float d2 = __fadd_rn(__fmul_rn(dx, dx), dy2);  // bit-exact ref
        if (d2 < R2f) {
            const int pix = (b << 14) | (h << 7) | w;
            const int pos = atomicAdd(cnt + pix, 1);
            if (pos < SLOTS)
                keys[(size_t)pix * SLOTS + pos] =
                    ((u64)__float_as_uint(pz) << 32) | (unsigned)p;
        }
    } else {
        // ---- transpose [C][P]->[P][C]: 256 blocks, each = (batch,
        // 64-point group, 32-channel half); R11-proven indexing.
        __shared__ float lt[32][65];
        const int tb  = blk - 512;             // 0..255
        const int b2  = tb >> 7;
        const int rem = tb & 127;
        const int p0  = (rem >> 1) << 6;       // 64-point group
        const int c0  = (rem & 1) << 5;        // channel half
        const int rr  = tidb >> 6;             // 0..3 (wave id)
        const int ccl = tidb & 63;
#pragma unroll
        for (int k = 0; k < 8; ++k) {
            const int c = k * 4 + rr;          // 0..31
            lt[c][ccl] = src[(size_t)((b2 * CC + c0 + c) << 12 | (p0 + ccl))];
        }
        __syncthreads();
        const int cch = tidb & 31;
        const int pl0 = tidb >> 5;             // 0..7
#pragma unroll
        for (int k = 0; k < 8; ++k) {
            const int pl = pl0 + k * 8;
            srcT[(size_t)(((b2 << 12) | (p0 + pl)) << 6) + c0 + cch] = lt[cch][pl];
        }
    }
}

// ---- Node 3: select + weights + composite + bg; CG=8, 1024 blocks ---------
// Block = 256 consecutive pixels x one 8-channel group (cg,b const per block).
// Load-batched gathers; LDS-staged float4 stores (2 dwordx4/thread).
__global__ __launch_bounds__(256) void selcomp_kernel(const float* __restrict__ pts,
                                                      const float* __restrict__ srcT,
                                                      const int* __restrict__ cnt,
                                                      const u64* __restrict__ keys,
                                                      float* __restrict__ out,
                                                      float* __restrict__ bgout) {
    const int t    = blockIdx.x * 256 + threadIdx.x;  // 0 .. BB*8*16384-1
    const int pix  = t & 16383;
    const int cg   = (t >> 14) & 7;                   // 8 groups of 8 channels
    const int b    = t >> 17;
    const int gpix = (b << 14) | pix;

    int n = cnt[gpix];
    n = (n > SLOTS) ? SLOTS : n;

    // ---- keys: vector-load first 4 slots; sort statically (no scratch)
    const u64* kp = keys + (size_t)gpix * SLOTS;
    const ulonglong2 k01 = *(const ulonglong2*)(kp + 0);
    const ulonglong2 k23 = *(const ulonglong2*)(kp + 2);

    u64 kk[KK];
#pragma unroll
    for (int s = 0; s < KK; ++s) kk[s] = EMPTYK;
#define INSK(KN) { u64 kn = (KN); \
    _Pragma("unroll") for (int s = 0; s < KK; ++s) \
        if (kn < kk[s]) { u64 tk = kk[s]; kk[s] = kn; kn = tk; } }
    if (0 < n) INSK(k01.x);
    if (1 < n) INSK(k01.y);
    if (2 < n) INSK(k23.x);
    if (3 < n) INSK(k23.y);
    for (int j = 4; j < n; ++j) INSK(kp[j]);          // rare (n>4)
#undef INSK

    const int nv = (n < KK) ? n : KK;

    // ---- batch gather: all pts + feature-line loads independent, exec-masked
    float qx[KK], qy[KK];
    float4 f0[KK], f1[KK];
#pragma unroll
    for (int s = 0; s < KK; ++s) {
        if (s < nv) {
            const int id = (int)(kk[s] & 0xffffffffu);
            const float* q = pts + (size_t)((b << 12) + id) * 3;
            qx[s] = q[0];
            qy[s] = q[1];
            const float* fp = srcT + ((size_t)((b << 12) + id) << 6) + cg * 8;
            f0[s] = *(const float4*)fp;
            f1[s] = *(const float4*)(fp + 4);
        }
    }

    const int w = pix & 127;
    const int h = pix >> 7;
    const float gx = 1.0f - (2 * w + 1) * (1.0f / 128.0f);
    const float gy = 1.0f - (2 * h + 1) * (1.0f / 128.0f);

    // ---- pure-VALU pass: exact d2, weights, transmittance chain, FMAs
    float acc[8];
#pragma unroll
    for (int c = 0; c < 8; ++c) acc[c] = 0.0f;
    float T = 1.0f;
#pragma unroll
    for (int s = 0; s < KK; ++s) {
        if (s < nv) {
            const float dx = __fadd_rn(gx, qx[s]);    // ref: gx - (-px)
            const float dy = __fadd_rn(gy, qy[s]);
            const float d2 = __fadd_rn(__fmul_rn(dx, dx), __fmul_rn(dy, dy));
            float dn = d2 / R2f;
            dn = fminf(fmaxf(dn, 0.001f), 1.0f);
            const float a  = 1.0f - sqrtf(dn);
            const float wt = a * T;
            T = T * (1.0f - a);
            acc[0] = fmaf(wt, f0[s].x, acc[0]);
            acc[1] = fmaf(wt, f0[s].y, acc[1]);
            acc[2] = fmaf(wt, f0[s].z, acc[2]);
            acc[3] = fmaf(wt, f0[s].w, acc[3]);
            acc[4] = fmaf(wt, f1[s].x, acc[4]);
            acc[5] = fmaf(wt, f1[s].y, acc[5]);
            acc[6] = fmaf(wt, f1[s].z, acc[6]);
            acc[7] = fmaf(wt, f1[s].w, acc[7]);
        }
    }

    // ---- LDS-staged stores: [8 ch][256 pix] then 2x float4 per thread
    __shared__ float sacc[8][256];
    const int lp = threadIdx.x;                // local pixel 0..255
#pragma unroll
    for (int c = 0; c < 8; ++c) sacc[c][lp] = acc[c];
    __syncthreads();
    {
        const int pixbase = pix & ~255;        // block's first pixel
#pragma unroll
        for (int k = 0; k < 2; ++k) {
            const int T2 = lp + k * 256;       // 0..511
            const int c  = T2 >> 6;            // 0..7
            const int qd = T2 & 63;            // 0..63 pixel-quad
            const float4 v = *(const float4*)&sacc[c][qd * 4];
            *(float4*)&out[((size_t)(b * CC + cg * 8 + c) << 14) |
                           (pixbase + qd * 4)] = v;
        }
    }

    // ---- background: dilate(cnt==0) over 3x3; one thread (cg==0) per pixel
    if (cg == 0) {
        int bgv = 0;
#pragma unroll
        for (int dh = -1; dh <= 1; ++dh)
#pragma unroll
            for (int dw = -1; dw <= 1; ++dw) {
                const int hh = h + dh, ww = w + dw;
                if (hh >= 0 && hh < 128 && ww >= 0 && ww < 128)
                    if (cnt[(b << 14) | (hh << 7) | ww] == 0) bgv = 1;
            }
        bgout[gpix] = bgv ? 1.0f : 0.0f;
    }
}

extern "C" void kernel_launch(void* const* d_in, const int* in_sizes, int n_in,
                              void* d_out, int out_size, void* d_ws, size_t ws_size,
                              hipStream_t stream) {
    const float* pts = (const float*)d_in[0];   // [B,P,3]
    const float* src = (const float*)d_in[1];   // [B,C,P]
    float* out = (float*)d_out;                 // [B,C,H,W] then bg [B,H,W]
    float* bgout = out + BB * CC * SZ * SZ;

    const int npix = BB * SZ * SZ;              // 32768
    char* ws = (char*)d_ws;
    float* srcT = (float*)ws;                                  // 2 MB
    int*   cnt  = (int*)(ws + (size_t)BB * PP * CC * 4);       // 128 KB
    u64*   keys = (u64*)(ws + (size_t)BB * PP * CC * 4 + (size_t)npix * 4); // 4 MB

    hipMemsetAsync(cnt, 0, (size_t)npix * 4, stream);
    prep_kernel<<<768, 256, 0, stream>>>(pts, src, srcT, cnt, keys);
    selcomp_kernel<<<(BB * 8 * SZ * SZ) / 256, 256, 0, stream>>>(
        pts, srcT, cnt, keys, out, bgout);
}

// Round 15
// 23.828 us; speedup vs baseline: 6.1240x; 1.0291x over previous
//
#include <hip/hip_runtime.h>
#include <math.h>

#define BB 2
#define PP 4096
#define CC 64
#define SZ 128
#define KK 8

// radius = 1.5/128*2 = 0.0234375 (exact); r^2 = 9*2^-14 (exact)
#define R2f 0.00054931640625f
#define SLOTS 16          // per-pixel slot cap (Poisson mean 1.77; P(>=16) ~ 1e-9)

typedef unsigned long long u64;
typedef float f4 __attribute__((ext_vector_type(4)));   // clang vector: OK for nontemporal
#define EMPTYK (~0ull)

// ---- Node 2: bin (blocks 0-511, 16 thr/point) + transpose (blocks 512-1023)
__global__ __launch_bounds__(256) void prep_kernel(const float* __restrict__ pts,
                                                   const float* __restrict__ src,
                                                   float* __restrict__ srcT,
                                                   int* __restrict__ cnt,
                                                   u64* __restrict__ keys) {
    const int tidb = threadIdx.x;
    const int blk  = blockIdx.x;

    if (blk < 512) {
        // ---- bin: 16 threads/point = (row 0..3) x (w-candidate 0..3).
        // Each thread: <=1 bit-exact test, <=1 atomic (chain depth 1).
        // unique totally-ordered (z_bits,idx) keys -> atomic order irrelevant.
        const int t  = blk * 256 + tidb;       // 0 .. BB*PP*16-1
        const int r  = t & 15;
        const int gp = t >> 4;                 // 0 .. BB*PP-1
        const int b  = gp >> 12;
        const int p  = gp & (PP - 1);
        const float px = pts[(size_t)gp * 3 + 0];
        const float py = pts[(size_t)gp * 3 + 1];
        const float pz = pts[(size_t)gp * 3 + 2];
        if (!(pz > 0.0f)) return;
        // gx(w) = 1-(2w+1)/128 equals -px at w = (1+px)*64 - 0.5
        const float u = (1.0f + px) * 64.0f - 0.5f;
        const float v = (1.0f + py) * 64.0f - 0.5f;
        const int wlo = max(0,   (int)ceilf (u - 1.53f));
        const int whi = min(127, (int)floorf(u + 1.53f));
        const int hlo = max(0,   (int)ceilf (v - 1.53f));
        const int hhi = min(127, (int)floorf(v + 1.53f));
        const int h = hlo + (r >> 2);
        const int w = wlo + (r & 3);
        if (h > hhi || w > whi) return;
        const float gy  = 1.0f - (2 * h + 1) * (1.0f / 128.0f);
        const float dy  = __fadd_rn(gy, py);   // ref: gy - (-py)
        const float dy2 = __fmul_rn(dy, dy);
        const float gx = 1.0f - (2 * w + 1) * (1.0f / 128.0f);
        const float dx = __fadd_rn(gx, px);
        const float d2 = __fadd_rn(__fmul_rn(dx, dx), dy2);  // bit-exact ref
        if (d2 < R2f) {
            const int pix = (b << 14) | (h << 7) | w;
            const int pos = atomicAdd(cnt + pix, 1);
            if (pos < SLOTS)
                keys[(size_t)pix * SLOTS + pos] =
                    ((u64)__float_as_uint(pz) << 32) | (unsigned)p;
        }
    } else {
        // ---- transpose [C][P]->[P][C]: 512 blocks, each = (batch,
        // 64-point group, 16-channel quarter)
        __shared__ float lt[16][65];
        const int tb  = blk - 512;             // 0..511
        const int b2  = tb >> 8;
        const int rem = tb & 255;
        const int p0  = (rem >> 2) << 6;       // 64-point group
        const int c0  = (rem & 3) << 4;        // channel quarter
        const int rr  = tidb >> 6;             // 0..3 (wave id)
        const int ccl = tidb & 63;
#pragma unroll
        for (int k = 0; k < 4; ++k) {
            const int c = k * 4 + rr;          // 0..15
            lt[c][ccl] = src[(size_t)((b2 * CC + c0 + c) << 12 | (p0 + ccl))];
        }
        __syncthreads();
        const int cch = tidb & 15;             // channel 0..15
        const int pl0 = tidb >> 4;             // 0..15
#pragma unroll
        for (int k = 0; k < 4; ++k) {
            const int pl = pl0 + k * 16;
            srcT[(size_t)(((b2 << 12) | (p0 + pl)) << 6) + c0 + cch] = lt[cch][pl];
        }
    }
}

// ---- Node 3: select + weights + composite + bg; CG=8, 1024 blocks ---------
// Block = 256 consecutive pixels x one 8-channel group (cg,b uniform/block).
// Load-batched gathers; bg cnt-loads hoisted to the front batch;
// LDS-staged nontemporal float4 stores.
__global__ __launch_bounds__(256) void selcomp_kernel(const float* __restrict__ pts,
                                                      const float* __restrict__ srcT,
                                                      const int* __restrict__ cnt,
                                                      const u64* __restrict__ keys,
                                                      float* __restrict__ out,
                                                      float* __restrict__ bgout) {
    const int t    = blockIdx.x * 256 + threadIdx.x;  // 0 .. BB*8*16384-1
    const int pix  = t & 16383;
    const int cg   = (t >> 14) & 7;                   // 8 groups of 8 channels
    const int b    = t >> 17;
    const int gpix = (b << 14) | pix;
    const int w = pix & 127;
    const int h = pix >> 7;

    int n = cnt[gpix];

    // ---- bg gather hoisted: 9 independent cnt loads (cg==0 blocks only)
    int bgc[9];
    if (cg == 0) {
#pragma unroll
        for (int di = 0; di < 3; ++di)
#pragma unroll
            for (int dj = 0; dj < 3; ++dj) {
                const int hh = h + di - 1, ww = w + dj - 1;
                bgc[di * 3 + dj] = (hh >= 0 && hh < 128 && ww >= 0 && ww < 128)
                                   ? cnt[(b << 14) | (hh << 7) | ww] : 1;
            }
    }

    n = (n > SLOTS) ? SLOTS : n;

    // ---- keys: vector-load first 4 slots; sort statically (no scratch)
    const u64* kp = keys + (size_t)gpix * SLOTS;
    const ulonglong2 k01 = *(const ulonglong2*)(kp + 0);
    const ulonglong2 k23 = *(const ulonglong2*)(kp + 2);

    u64 kk[KK];
#pragma unroll
    for (int s = 0; s < KK; ++s) kk[s] = EMPTYK;
#define INSK(KN) { u64 kn = (KN); \
    _Pragma("unroll") for (int s = 0; s < KK; ++s) \
        if (kn < kk[s]) { u64 tk = kk[s]; kk[s] = kn; kn = tk; } }
    if (0 < n) INSK(k01.x);
    if (1 < n) INSK(k01.y);
    if (2 < n) INSK(k23.x);
    if (3 < n) INSK(k23.y);
    for (int j = 4; j < n; ++j) INSK(kp[j]);          // rare (n>4)
#undef INSK

    const int nv = (n < KK) ? n : KK;

    // ---- batch gather: all pts + feature-line loads independent, exec-masked
    float qx[KK], qy[KK];
    float4 f0[KK], f1[KK];
#pragma unroll
    for (int s = 0; s < KK; ++s) {
        if (s < nv) {
            const int id = (int)(kk[s] & 0xffffffffu);
            const float* q = pts + (size_t)((b << 12) + id) * 3;
            qx[s] = q[0];
            qy[s] = q[1];
            const float* fp = srcT + ((size_t)((b << 12) + id) << 6) + cg * 8;
            f0[s] = *(const float4*)fp;
            f1[s] = *(const float4*)(fp + 4);
        }
    }

    const float gx = 1.0f - (2 * w + 1) * (1.0f / 128.0f);
    const float gy = 1.0f - (2 * h + 1) * (1.0f / 128.0f);

    // ---- pure-VALU pass: exact d2, weights, transmittance chain, FMAs
    float acc[8];
#pragma unroll
    for (int c = 0; c < 8; ++c) acc[c] = 0.0f;
    float T = 1.0f;
#pragma unroll
    for (int s = 0; s < KK; ++s) {
        if (s < nv) {
            const float dx = __fadd_rn(gx, qx[s]);    // ref: gx - (-px)
            const float dy = __fadd_rn(gy, qy[s]);
            const float d2 = __fadd_rn(__fmul_rn(dx, dx), __fmul_rn(dy, dy));
            float dn = d2 / R2f;
            dn = fminf(fmaxf(dn, 0.001f), 1.0f);
            const float a  = 1.0f - sqrtf(dn);
            const float wt = a * T;
            T = T * (1.0f - a);
            acc[0] = fmaf(wt, f0[s].x, acc[0]);
            acc[1] = fmaf(wt, f0[s].y, acc[1]);
            acc[2] = fmaf(wt, f0[s].z, acc[2]);
            acc[3] = fmaf(wt, f0[s].w, acc[3]);
            acc[4] = fmaf(wt, f1[s].x, acc[4]);
            acc[5] = fmaf(wt, f1[s].y, acc[5]);
            acc[6] = fmaf(wt, f1[s].z, acc[6]);
            acc[7] = fmaf(wt, f1[s].w, acc[7]);
        }
    }

    // ---- LDS-staged stores: [8 ch][256 pix] then 2x nontemporal f4
    __shared__ float sacc[8][256];
    const int lp = threadIdx.x;                // local pixel 0..255
#pragma unroll
    for (int c = 0; c < 8; ++c) sacc[c][lp] = acc[c];
    __syncthreads();
    {
        const int pixbase = pix & ~255;        // block's first pixel
#pragma unroll
        for (int k = 0; k < 2; ++k) {
            const int T2 = lp + k * 256;       // 0..511
            const int c  = T2 >> 6;            // 0..7
            const int qd = T2 & 63;            // 0..63 pixel-quad
            const f4 v = *(const f4*)&sacc[c][qd * 4];
            __builtin_nontemporal_store(v,
                (f4*)&out[((size_t)(b * CC + cg * 8 + c) << 14) |
                          (pixbase + qd * 4)]);
        }
    }

    // ---- background: dilate(cnt==0) over 3x3 from the hoisted batch
    if (cg == 0) {
        int bgv = 0;
#pragma unroll
        for (int i = 0; i < 9; ++i) bgv |= (bgc[i] == 0);
        __builtin_nontemporal_store(bgv ? 1.0f : 0.0f, &bgout[gpix]);
    }
}

extern "C" void kernel_launch(void* const* d_in, const int* in_sizes, int n_in,
                              void* d_out, int out_size, void* d_ws, size_t ws_size,
                              hipStream_t stream) {
    const float* pts = (const float*)d_in[0];   // [B,P,3]
    const float* src = (const float*)d_in[1];   // [B,C,P]
    float* out = (float*)d_out;                 // [B,C,H,W] then bg [B,H,W]
    float* bgout = out + BB * CC * SZ * SZ;

    const int npix = BB * SZ * SZ;              // 32768
    char* ws = (char*)d_ws;
    float* srcT = (float*)ws;                                  // 2 MB
    int*   cnt  = (int*)(ws + (size_t)BB * PP * CC * 4);       // 128 KB
    u64*   keys = (u64*)(ws + (size_t)BB * PP * CC * 4 + (size_t)npix * 4); // 4 MB

    (void)hipMemsetAsync(cnt, 0, (size_t)npix * 4, stream);
    prep_kernel<<<1024, 256, 0, stream>>>(pts, src, srcT, cnt, keys);
    selcomp_kernel<<<(BB * 8 * SZ * SZ) / 256, 256, 0, stream>>>(
        pts, srcT, cnt, keys, out, bgout);
}